// Round 7
// baseline (178.658 us; speedup 1.0000x reference)
//
#include <hip/hip_runtime.h>
#include <stdint.h>

// Problem constants (from reference): B=4, N=8192, D=512, H=8, Dh=64
#define SEQ      8192
#define BATCH    4
#define DIM      512
#define MROWS    32768      // BATCH*SEQ
#define CHUNK    64
#define NCHUNK   128        // SEQ / CHUNK (per batch); 512 global chunks
#define NCHAN    2048       // BATCH * DIM
#define NHEAD    8
#define NGCHUNK  512        // BATCH * NCHUNK
#define XLD      264        // X tile row stride (256 + 8 pad)
#define NITER    16         // DIM / 32 K-steps

typedef unsigned short ushort;
typedef unsigned int   uint;
typedef __bf16 bf16x8 __attribute__((ext_vector_type(8)));
typedef float  f32x4  __attribute__((ext_vector_type(4)));
typedef ushort usx8   __attribute__((ext_vector_type(8)));

// native RNE f32->bf16 (hardware cvt)
__device__ __forceinline__ ushort f2bf(float f) {
    union { __bf16 h; ushort u; } cv;
    cv.h = (__bf16)f;
    return cv.u;
}
__device__ __forceinline__ float bf2f(ushort v) {
    return __uint_as_float(((unsigned)v) << 16);
}

// both weight matrices in one launch; outputs contiguous (win_bf then wout_bf)
__global__ void weights_to_bf16_kernel(const float* __restrict__ w_in,
                                       const float* __restrict__ w_out,
                                       ushort* __restrict__ dst, int n4each) {
    int i = blockIdx.x * blockDim.x + threadIdx.x;
    if (i >= 2 * n4each) return;
    const float4* src = (i < n4each) ? (const float4*)w_in
                                     : (const float4*)w_out - n4each;
    float4 v = src[i];
    ushort4 r;
    r.x = f2bf(v.x); r.y = f2bf(v.y); r.z = f2bf(v.z); r.w = f2bf(v.w);
    ((ushort4*)dst)[i] = r;
}

#define GLDS(g, l) __builtin_amdgcn_global_load_lds(                        \
        (const __attribute__((address_space(1))) void*)(g),                 \
        (__attribute__((address_space(3))) void*)(l), 16, 0, 0)

#define WAITV(n)  asm volatile("s_waitcnt vmcnt(" #n ")" ::: "memory")
#define WAITL0()  asm volatile("s_waitcnt lgkmcnt(0)" ::: "memory")
#define BAR()     do { __builtin_amdgcn_s_barrier();                        \
                       __builtin_amdgcn_sched_barrier(0); } while (0)
#define SBAR()    __builtin_amdgcn_sched_barrier(0)

// LDS XOR swizzle (T2, adapted to 64-B rows / BK=32): within each row's
// four 16-B slots, content of k-quad q lives at slot (q ^ (row&3)).
// Kills the 4-way per-phase bank conflict of ds_read_b128 fragment reads
// (lanes r and r+4 previously hit the same 16-B slot). A-side: swizzle
// both ds_write and ds_read addresses. B-side (GLDS writes linearly):
// pre-swizzle the GLOBAL source k-offset; read with the same XOR (rule 21).

// =====================================================================
// GEMM1 + fused chunk-local scan
//   xp = x @ W_in^T + b_in  (tile kept in LDS, never written to global)
//   z_loc'[t] = c*z' + alpha*(xp[t]-xp[t-1]), prev=0 at chunk start
//   writes: z_loc' (bf16), L' = chunk tail (f32), XpT[g+1] = xp tail (f32)
//   Cross-chunk carry applied in GEMM2: z = z_loc' + c^tau * G.
// K-loop: 3-buffer rotation, counted vmcnt, raw s_barrier; stage-issue
// AFTER the barrier (round-6 race fix).
// =====================================================================
__global__ __launch_bounds__(512, 4) void gemm1_scan_kernel(
        const float* __restrict__ x,    const ushort* __restrict__ Bw,
        const float* __restrict__ b_in, const float* __restrict__ alpha_param,
        ushort* __restrict__ zout,
        float* __restrict__ Lfin,       float* __restrict__ XpT)
{
    // LDS: 3x(8KB As + 16KB Bs) = 72 KB, overlaid with X[128][XLD] (66 KB)
    __shared__ __align__(16) char smem[73728];
    ushort* As0 = (ushort*)smem;                 // 3 bufs x 4096 ushorts
    ushort* Bs0 = (ushort*)(smem + 24576);       // 3 bufs x 8192 ushorts
    ushort* X   = (ushort*)smem;                 // [128][XLD] (epilogue)

    const int tid = threadIdx.x;            // 0..511
    const int bn  = blockIdx.x;             // 0..1
    const int bm  = blockIdx.y;             // 0..255

    const int lane = tid & 63;
    const int wave = tid >> 6;
    const int wr = wave >> 2, wc = wave & 3;
    const int quad = lane >> 4, r16 = lane & 15;

    // staging map: thread -> row = tid>>2 (0..127), k-slot = tid&3
    const int srow  = tid >> 2;
    const int ks    = tid & 3;
    const int rx    = srow & 3;             // row-XOR for swizzle
    const int skoff = ks * 8;               // A content k-offset (unswizzled)
    const float*  Ag  = x  + (size_t)(bm * 128 + srow) * DIM + skoff;
    // B global source pre-swizzled: linear LDS slot ks receives quad ks^rx
    const ushort* Bg0 = Bw + (size_t)(bn * 256 + srow) * DIM + ((ks ^ rx) << 3);
    const ushort* Bg1 = Bg0 + (size_t)128 * DIM;
    // A ds_write slot (swizzled address, content = quad ks)
    const int aWrOff = srow * 32 + ((ks ^ rx) << 3);

    f32x4 acc[4][4];
    #pragma unroll
    for (int i = 0; i < 4; i++)
        #pragma unroll
        for (int j = 0; j < 4; j++)
            acc[i][j] = f32x4{0.f, 0.f, 0.f, 0.f};

    auto stageB = [&](int k0, int b) {
        GLDS(Bg0 + k0, &Bs0[b * 8192 + tid * 8]);
        GLDS(Bg1 + k0, &Bs0[b * 8192 + 4096 + tid * 8]);
    };
    auto packA = [&](float4 lo, float4 hi) {
        usx8 w;
        w[0] = f2bf(lo.x); w[1] = f2bf(lo.y); w[2] = f2bf(lo.z); w[3] = f2bf(lo.w);
        w[4] = f2bf(hi.x); w[5] = f2bf(hi.y); w[6] = f2bf(hi.z); w[7] = f2bf(hi.w);
        return w;
    };

    // A reg sets: data for buf j lives in set (j&1)
    float4 aLo0, aHi0, aLo1, aHi1;

    // prologue: issue stages for bufs 0 and 1; write As[0]
    aLo0 = *(const float4*)(Ag);      aHi0 = *(const float4*)(Ag + 4);
    stageB(0, 0);
    aLo1 = *(const float4*)(Ag + 32); aHi1 = *(const float4*)(Ag + 36);
    stageB(32, 1);
    *(usx8*)&As0[aWrOff] = packA(aLo0, aHi0);    // compiler auto-waits regs

    // fragment-read swizzle: row&3 == r16&3 for all i/j tiles
    const int rxr = r16 & 3;

    #pragma unroll
    for (int k = 0; k < NITER; ++k) {
        const int cur = k % 3;
        const int stg = (k + 2) % 3;
        const int wnx = (k + 1) % 3;

        // P2: ds_write A for buf k+1 (regs loaded at iter k-1 / prologue).
        if (k + 1 < NITER) {
            usx8 w = ((k & 1) == 0) ? packA(aLo1, aHi1) : packA(aLo0, aHi0);
            *(usx8*)&As0[wnx * 4096 + aWrOff] = w;
        }
        // counted vm backstop + lgkm drain (own ds_write) + rendezvous
        if (k < NITER - 1) WAITV(4); else WAITV(0);
        WAITL0();
        BAR();

        // P1 (POST-BAR): issue stage for buf k+2
        if (k + 2 < NITER) {
            const int ko = (k + 2) * 32;
            if ((k & 1) == 0) {
                aLo0 = *(const float4*)(Ag + ko); aHi0 = *(const float4*)(Ag + ko + 4);
            } else {
                aLo1 = *(const float4*)(Ag + ko); aHi1 = *(const float4*)(Ag + ko + 4);
            }
            SBAR();
            stageB(ko, stg);
        }

        bf16x8 af[4], bfr[4];
        #pragma unroll
        for (int i = 0; i < 4; i++)
            af[i] = *(const bf16x8*)&As0[cur * 4096 + (wr * 64 + i * 16 + r16) * 32
                                         + ((quad ^ rxr) << 3)];
        #pragma unroll
        for (int j = 0; j < 4; j++)
            bfr[j] = *(const bf16x8*)&Bs0[cur * 8192 + (wc * 64 + j * 16 + r16) * 32
                                          + ((quad ^ rxr) << 3)];

        #pragma unroll
        for (int i = 0; i < 4; i++)
            #pragma unroll
            for (int j = 0; j < 4; j++)
                acc[i][j] = __builtin_amdgcn_mfma_f32_16x16x32_bf16(
                                bfr[j], af[i], acc[i][j], 0, 0, 0);  // swapped
    }

    // ---- epilogue part 1: xp tile (C + bias) -> LDS X[128][XLD] (bf16)
    __syncthreads();   // full drain; all waves done reading As/Bs
    #pragma unroll
    for (int i = 0; i < 4; i++) {
        const int ml = wr * 64 + i * 16 + r16;
        #pragma unroll
        for (int j = 0; j < 4; j++) {
            const int nl = wc * 64 + j * 16 + quad * 4;
            const float4 bv = *(const float4*)&b_in[bn * 256 + nl];
            ushort4 r4;
            r4.x = f2bf(acc[i][j][0] + bv.x);
            r4.y = f2bf(acc[i][j][1] + bv.y);
            r4.z = f2bf(acc[i][j][2] + bv.z);
            r4.w = f2bf(acc[i][j][3] + bv.w);
            *(ushort4*)&X[ml * XLD + nl] = r4;
        }
    }
    __syncthreads();

    // ---- epilogue part 2: chunk-local scan (prev = 0 at chunk start)
    const int chalf = tid >> 8;             // 0..1
    const int cidx  = tid & 255;            // 0..255
    const int g     = 2 * bm + chalf;       // global chunk 0..511
    const int d     = bn * 256 + cidx;      // 0..511
    const int h     = d >> 6;
    const float alpha = 1.0f / (1.0f + expf(-alpha_param[h]));
    const float c     = 1.0f - alpha;

    const ushort* Xr  = X + chalf * 64 * XLD + cidx;
    ushort* zrow = zout + ((size_t)(bm * 128 + chalf * 64)) * DIM + d;

    float z = 0.f, prev = 0.f;
    #pragma unroll 8
    for (int r = 0; r < CHUNK; ++r) {
        float xv = bf2f(Xr[r * XLD]);
        z = c * z + alpha * (xv - prev);
        prev = xv;
        zrow[(size_t)r * DIM] = f2bf(z);
    }
    Lfin[(size_t)g * 512 + d]       = z;     // L' tail
    XpT[(size_t)(g + 1) * 512 + d]  = prev;  // xp tail -> next chunk's xpt
}

// =====================================================================
// Carry chain:  G_k = c*Z_k - alpha*xpt_k ;  Z_{k+1} = L'_k + c^63 * G_k
// =====================================================================
__global__ void scan_fixg_kernel(const float* __restrict__ Lfin,
                                 const float* __restrict__ XpT,
                                 const float* __restrict__ alpha_param,
                                 const float* __restrict__ init_state,
                                 float* __restrict__ G)
{
    int ch = blockIdx.x * blockDim.x + threadIdx.x;   // 0..2047
    if (ch >= NCHAN) return;
    const int b = ch >> 9;
    const int d = ch & (DIM - 1);
    const int h = d >> 6;
    const float alpha = 1.0f / (1.0f + expf(-alpha_param[h]));
    const float c = 1.0f - alpha;
    const float c2 = c * c, c4 = c2 * c2, c8 = c4 * c4,
                c16 = c8 * c8, c32 = c16 * c16;
    const float c63 = c32 * c16 * c8 * c4 * c2 * c;
    const float sinit = init_state[d];

    float Z = sinit;
    const float* Lp = Lfin + (size_t)(b * NCHUNK) * 512 + d;
    const float* Xp = XpT  + (size_t)(b * NCHUNK) * 512 + d;
    float*       Gp = G    + (size_t)(b * NCHUNK) * 512 + d;

    constexpr int PF = 16;
    float Lr[PF], Xr[PF];
    #pragma unroll
    for (int j = 0; j < PF; ++j) {
        Lr[j] = Lp[(size_t)j * 512];
        Xr[j] = Xp[(size_t)j * 512];
    }
    for (int gr = 0; gr < NCHUNK / PF; ++gr) {        // 8 groups
        #pragma unroll
        for (int j = 0; j < PF; ++j) {
            const int kl = gr * PF + j;
            const float xpt = (kl == 0) ? sinit : Xr[j];
            const float Lc  = Lr[j];
            if (gr + 1 < NCHUNK / PF) {
                Lr[j] = Lp[(size_t)((gr + 1) * PF + j) * 512];
                Xr[j] = Xp[(size_t)((gr + 1) * PF + j) * 512];
            }
            const float Gv = c * Z - alpha * xpt;
            Gp[(size_t)kl * 512] = Gv;
            Z = Lc + c63 * Gv;
        }
    }
}

// =====================================================================
// GEMM2: out = z @ W_out^T + b_out ; carry correction fused in A-staging:
//   a[tau, d] += c_h^tau * G[g][d]   (g = row>>6, tau = row&63)
// Same race-fixed 3-buffer loop + LDS XOR swizzle.
// =====================================================================
__global__ __launch_bounds__(512, 4) void gemm2_kernel(
        const ushort* __restrict__ Az, const ushort* __restrict__ Bw,
        const float* __restrict__ bias, float* __restrict__ Cout,
        const float* __restrict__ G, const float* __restrict__ alpha_param)
{
    __shared__ __align__(16) char smem[73728];
    ushort* As0 = (ushort*)smem;                 // 3 bufs x 4096 ushorts
    ushort* Bs0 = (ushort*)(smem + 24576);       // 3 bufs x 8192 ushorts

    const int tid  = threadIdx.x;
    const int lane = tid & 63;
    const int wave = tid >> 6;
    const int wr = wave >> 2, wc = wave & 3;
    const int bm = blockIdx.y, bn = blockIdx.x;
    const int quad = lane >> 4, r16 = lane & 15;

    const int srow  = tid >> 2;
    const int ks    = tid & 3;
    const int rx    = srow & 3;
    const int skoff = ks * 8;               // content k-offset
    const ushort* Ag16 = Az + (size_t)(bm * 128 + srow) * DIM + skoff;
    const ushort* Bg0  = Bw + (size_t)(bn * 256 + srow) * DIM + ((ks ^ rx) << 3);
    const ushort* Bg1  = Bg0 + (size_t)128 * DIM;
    const int aWrOff = srow * 32 + ((ks ^ rx) << 3);

    // per-thread fixed row -> fixed (g, tau); c_h^tau as named scalars
    const int m   = bm * 128 + srow;
    const int tau = m & (CHUNK - 1);
    const float* Gc = G + (size_t)(m >> 6) * 512;
    const float t1 = (float)tau;
    float fc0,fc1,fc2,fc3,fc4,fc5,fc6,fc7;
    {
        float a, c;
        a = 1.f/(1.f+expf(-alpha_param[0])); c = 1.f - a; fc0 = exp2f(t1 * log2f(c));
        a = 1.f/(1.f+expf(-alpha_param[1])); c = 1.f - a; fc1 = exp2f(t1 * log2f(c));
        a = 1.f/(1.f+expf(-alpha_param[2])); c = 1.f - a; fc2 = exp2f(t1 * log2f(c));
        a = 1.f/(1.f+expf(-alpha_param[3])); c = 1.f - a; fc3 = exp2f(t1 * log2f(c));
        a = 1.f/(1.f+expf(-alpha_param[4])); c = 1.f - a; fc4 = exp2f(t1 * log2f(c));
        a = 1.f/(1.f+expf(-alpha_param[5])); c = 1.f - a; fc5 = exp2f(t1 * log2f(c));
        a = 1.f/(1.f+expf(-alpha_param[6])); c = 1.f - a; fc6 = exp2f(t1 * log2f(c));
        a = 1.f/(1.f+expf(-alpha_param[7])); c = 1.f - a; fc7 = exp2f(t1 * log2f(c));
    }
    auto selfac = [&](int hh) -> float {
        float f = fc0;
        f = (hh == 1) ? fc1 : f;
        f = (hh == 2) ? fc2 : f;
        f = (hh == 3) ? fc3 : f;
        f = (hh == 4) ? fc4 : f;
        f = (hh == 5) ? fc5 : f;
        f = (hh == 6) ? fc6 : f;
        f = (hh == 7) ? fc7 : f;
        return f;
    };
    auto fixpack = [&](usx8 av, float4 z0, float4 z1, float fac) {
        usx8 w;
        w[0] = f2bf(bf2f(av[0]) + fac * z0.x);
        w[1] = f2bf(bf2f(av[1]) + fac * z0.y);
        w[2] = f2bf(bf2f(av[2]) + fac * z0.z);
        w[3] = f2bf(bf2f(av[3]) + fac * z0.w);
        w[4] = f2bf(bf2f(av[4]) + fac * z1.x);
        w[5] = f2bf(bf2f(av[5]) + fac * z1.y);
        w[6] = f2bf(bf2f(av[6]) + fac * z1.z);
        w[7] = f2bf(bf2f(av[7]) + fac * z1.w);
        return w;
    };

    f32x4 acc[4][4];
    #pragma unroll
    for (int i = 0; i < 4; i++)
        #pragma unroll
        for (int j = 0; j < 4; j++)
            acc[i][j] = f32x4{0.f, 0.f, 0.f, 0.f};

    auto stageB = [&](int k0, int b) {
        GLDS(Bg0 + k0, &Bs0[b * 8192 + tid * 8]);
        GLDS(Bg1 + k0, &Bs0[b * 8192 + 4096 + tid * 8]);
    };

    // A reg sets: data for buf j in set (j&1)
    usx8 av0, av1; float4 g0lo, g0hi, g1lo, g1hi;

    // prologue: issue stages for bufs 0,1; write fixed As[0]
    av0 = *(const usx8*)(Ag16);
    g0lo = *(const float4*)&Gc[skoff]; g0hi = *(const float4*)&Gc[skoff + 4];
    stageB(0, 0);
    av1 = *(const usx8*)(Ag16 + 32);
    g1lo = *(const float4*)&Gc[32 + skoff]; g1hi = *(const float4*)&Gc[32 + skoff + 4];
    stageB(32, 1);
    *(usx8*)&As0[aWrOff] = fixpack(av0, g0lo, g0hi, selfac(skoff >> 6));

    const int rxr = r16 & 3;

    #pragma unroll
    for (int k = 0; k < NITER; ++k) {
        const int cur = k % 3;
        const int stg = (k + 2) % 3;
        const int wnx = (k + 1) % 3;

        // P2: ds_write fixed A for buf k+1 (regs loaded at iter k-1)
        if (k + 1 < NITER) {
            const float fac = selfac((((k + 1) * 32) + skoff) >> 6);
            usx8 w = ((k & 1) == 0) ? fixpack(av1, g1lo, g1hi, fac)
                                    : fixpack(av0, g0lo, g0hi, fac);
            *(usx8*)&As0[wnx * 4096 + aWrOff] = w;
        }
        if (k < NITER - 1) WAITV(5); else WAITV(0);
        WAITL0();
        BAR();

        // P1 (POST-BAR): issue stage for buf k+2
        if (k + 2 < NITER) {
            const int ko = (k + 2) * 32;
            if ((k & 1) == 0) {
                av0 = *(const usx8*)(Ag16 + ko);
                g0lo = *(const float4*)&Gc[ko + skoff];
                g0hi = *(const float4*)&Gc[ko + skoff + 4];
            } else {
                av1 = *(const usx8*)(Ag16 + ko);
                g1lo = *(const float4*)&Gc[ko + skoff];
                g1hi = *(const float4*)&Gc[ko + skoff + 4];
            }
            SBAR();
            stageB(ko, stg);
        }

        bf16x8 af[4], bfr[4];
        #pragma unroll
        for (int i = 0; i < 4; i++)
            af[i] = *(const bf16x8*)&As0[cur * 4096 + (wr * 64 + i * 16 + r16) * 32
                                         + ((quad ^ rxr) << 3)];
        #pragma unroll
        for (int j = 0; j < 4; j++)
            bfr[j] = *(const bf16x8*)&Bs0[cur * 8192 + (wc * 64 + j * 16 + r16) * 32
                                          + ((quad ^ rxr) << 3)];

        #pragma unroll
        for (int i = 0; i < 4; i++)
            #pragma unroll
            for (int j = 0; j < 4; j++)
                acc[i][j] = __builtin_amdgcn_mfma_f32_16x16x32_bf16(
                                bfr[j], af[i], acc[i][j], 0, 0, 0);  // swapped
    }

    // epilogue: m = lane&15 (per i-tile), n = quad*4 + reg
    #pragma unroll
    for (int i = 0; i < 4; i++) {
        const int mr = bm * 128 + wr * 64 + i * 16 + r16;
        #pragma unroll
        for (int j = 0; j < 4; j++) {
            const int n0 = bn * 256 + wc * 64 + j * 16 + quad * 4;
            const float4 bv = *(const float4*)&bias[n0];
            float4 v = make_float4(acc[i][j][0] + bv.x, acc[i][j][1] + bv.y,
                                   acc[i][j][2] + bv.z, acc[i][j][3] + bv.w);
            *(float4*)&Cout[(size_t)mr * DIM + n0] = v;
        }
    }
}

extern "C" void kernel_launch(void* const* d_in, const int* in_sizes, int n_in,
                              void* d_out, int out_size, void* d_ws, size_t ws_size,
                              hipStream_t stream) {
    const float* x           = (const float*)d_in[0];
    const float* W_in        = (const float*)d_in[1];
    const float* b_in        = (const float*)d_in[2];
    const float* W_out       = (const float*)d_in[3];
    const float* b_out       = (const float*)d_in[4];
    const float* init_state  = (const float*)d_in[5];
    const float* alpha_param = (const float*)d_in[6];
    float* out = (float*)d_out;

    // workspace layout
    ushort* z_bf    = (ushort*)d_ws;                       // 32 MB
    ushort* win_bf  = z_bf   + (size_t)MROWS * DIM;        // 0.5 MB
    ushort* wout_bf = win_bf + (size_t)DIM * DIM;          // 0.5 MB
    float*  Lfin    = (float*)(wout_bf + (size_t)DIM * DIM);        // [512][512]
    float*  XpT     = Lfin + (size_t)NGCHUNK * 512;                 // [513][512]
    float*  G       = XpT  + (size_t)(NGCHUNK + 1) * 512;           // [512][512]

    const int nw4 = (DIM * DIM) / 4;          // 65,536
    weights_to_bf16_kernel<<<(2 * nw4 + 255) / 256, 256, 0, stream>>>(
        W_in, W_out, win_bf, nw4);

    dim3 g1(2, MROWS / 128);                  // (2, 256)
    gemm1_scan_kernel<<<g1, 512, 0, stream>>>(
        x, win_bf, b_in, alpha_param, z_bf, Lfin, XpT);

    scan_fixg_kernel<<<NCHAN / 256, 256, 0, stream>>>(
        Lfin, XpT, alpha_param, init_state, G);

    dim3 g2(2, MROWS / 128);                  // (2, 256)
    gemm2_kernel<<<g2, 512, 0, stream>>>(
        z_bf, wout_bf, b_out, out, G, alpha_param);
}

// Round 8
// 175.262 us; speedup vs baseline: 1.0194x; 1.0194x over previous
//
#include <hip/hip_runtime.h>
#include <stdint.h>

// Problem constants (from reference): B=4, N=8192, D=512, H=8, Dh=64
#define SEQ      8192
#define BATCH    4
#define DIM      512
#define MROWS    32768      // BATCH*SEQ
#define CHUNK    64
#define NCHUNK   128        // SEQ / CHUNK (per batch); 512 global chunks
#define NCHAN    2048       // BATCH * DIM
#define NHEAD    8
#define NGCHUNK  512        // BATCH * NCHUNK
#define XLD      264        // X tile row stride (256 + 8 pad)
#define NITER    16         // DIM / 32 K-steps

typedef unsigned short ushort;
typedef unsigned int   uint;
typedef __bf16 bf16x8 __attribute__((ext_vector_type(8)));
typedef float  f32x4  __attribute__((ext_vector_type(4)));
typedef ushort usx8   __attribute__((ext_vector_type(8)));

// native RNE f32->bf16 (hardware cvt)
__device__ __forceinline__ ushort f2bf(float f) {
    union { __bf16 h; ushort u; } cv;
    cv.h = (__bf16)f;
    return cv.u;
}
__device__ __forceinline__ float bf2f(ushort v) {
    return __uint_as_float(((unsigned)v) << 16);
}

// both weight matrices in one launch; outputs contiguous (win_bf then wout_bf)
__global__ void weights_to_bf16_kernel(const float* __restrict__ w_in,
                                       const float* __restrict__ w_out,
                                       ushort* __restrict__ dst, int n4each) {
    int i = blockIdx.x * blockDim.x + threadIdx.x;
    if (i >= 2 * n4each) return;
    const float4* src = (i < n4each) ? (const float4*)w_in
                                     : (const float4*)w_out - n4each;
    float4 v = src[i];
    ushort4 r;
    r.x = f2bf(v.x); r.y = f2bf(v.y); r.z = f2bf(v.z); r.w = f2bf(v.w);
    ((ushort4*)dst)[i] = r;
}

#define GLDS(g, l) __builtin_amdgcn_global_load_lds(                        \
        (const __attribute__((address_space(1))) void*)(g),                 \
        (__attribute__((address_space(3))) void*)(l), 16, 0, 0)

#define WAITV(n)  asm volatile("s_waitcnt vmcnt(" #n ")" ::: "memory")
#define WAITL0()  asm volatile("s_waitcnt lgkmcnt(0)" ::: "memory")
#define BAR()     do { __builtin_amdgcn_s_barrier();                        \
                       __builtin_amdgcn_sched_barrier(0); } while (0)
#define SBAR()    __builtin_amdgcn_sched_barrier(0)

// LDS XOR swizzle, CORRECTED bits (round 7 used row&3 -> measured no-op):
// a 64-B row spans 16 banks, so the bank pattern repeats every 2 rows and
// the aliasing set within a quad is rows {r, r+4, r+8, r+12}. group(lane) =
// 16*(row&1) + 4*slot. Free (2-way) placement needs slot = quad ^ ((row>>1)&3):
// even rows then take slots 0,1,2,3,0,1,2,3 across the quad -> every 4-bank
// group hit exactly twice. Write side uses (srow>>1)&3; (row+128) preserves
// the XOR so one map serves both B half-tiles; on the read side
// ((16m + r16)>>1)&3 == (r16>>1)&3, so fragment reads use (r16>>1)&3.

// =====================================================================
// GEMM1 + fused chunk-local scan
//   xp = x @ W_in^T + b_in  (tile kept in LDS, never written to global)
//   z_loc'[t] = c*z' + alpha*(xp[t]-xp[t-1]), prev=0 at chunk start
//   writes: z_loc' (bf16), L' = chunk tail (f32), XpT[g+1] = xp tail (f32)
//   Cross-chunk carry applied in GEMM2: z = z_loc' + c^tau * G.
// K-loop: 3-buffer rotation, counted vmcnt, raw s_barrier; stage-issue
// AFTER the barrier (round-6 race fix).
// =====================================================================
__global__ __launch_bounds__(512, 4) void gemm1_scan_kernel(
        const float* __restrict__ x,    const ushort* __restrict__ Bw,
        const float* __restrict__ b_in, const float* __restrict__ alpha_param,
        ushort* __restrict__ zout,
        float* __restrict__ Lfin,       float* __restrict__ XpT)
{
    // LDS: 3x(8KB As + 16KB Bs) = 72 KB, overlaid with X[128][XLD] (66 KB)
    __shared__ __align__(16) char smem[73728];
    ushort* As0 = (ushort*)smem;                 // 3 bufs x 4096 ushorts
    ushort* Bs0 = (ushort*)(smem + 24576);       // 3 bufs x 8192 ushorts
    ushort* X   = (ushort*)smem;                 // [128][XLD] (epilogue)

    const int tid = threadIdx.x;            // 0..511
    const int bn  = blockIdx.x;             // 0..1
    const int bm  = blockIdx.y;             // 0..255

    const int lane = tid & 63;
    const int wave = tid >> 6;
    const int wr = wave >> 2, wc = wave & 3;
    const int quad = lane >> 4, r16 = lane & 15;

    // staging map: thread -> row = tid>>2 (0..127), k-slot = tid&3
    const int srow  = tid >> 2;
    const int ks    = tid & 3;
    const int rx    = (srow >> 1) & 3;      // row-XOR (bits 1-2!)
    const int skoff = ks * 8;               // A content k-offset (unswizzled)
    const float*  Ag  = x  + (size_t)(bm * 128 + srow) * DIM + skoff;
    // B global source pre-swizzled: linear LDS slot ks receives quad ks^rx
    const ushort* Bg0 = Bw + (size_t)(bn * 256 + srow) * DIM + ((ks ^ rx) << 3);
    const ushort* Bg1 = Bg0 + (size_t)128 * DIM;
    // A ds_write slot (swizzled address, content = quad ks)
    const int aWrOff = srow * 32 + ((ks ^ rx) << 3);

    f32x4 acc[4][4];
    #pragma unroll
    for (int i = 0; i < 4; i++)
        #pragma unroll
        for (int j = 0; j < 4; j++)
            acc[i][j] = f32x4{0.f, 0.f, 0.f, 0.f};

    auto stageB = [&](int k0, int b) {
        GLDS(Bg0 + k0, &Bs0[b * 8192 + tid * 8]);
        GLDS(Bg1 + k0, &Bs0[b * 8192 + 4096 + tid * 8]);
    };
    auto packA = [&](float4 lo, float4 hi) {
        usx8 w;
        w[0] = f2bf(lo.x); w[1] = f2bf(lo.y); w[2] = f2bf(lo.z); w[3] = f2bf(lo.w);
        w[4] = f2bf(hi.x); w[5] = f2bf(hi.y); w[6] = f2bf(hi.z); w[7] = f2bf(hi.w);
        return w;
    };

    // A reg sets: data for buf j lives in set (j&1)
    float4 aLo0, aHi0, aLo1, aHi1;

    // prologue: issue stages for bufs 0 and 1; write As[0]
    aLo0 = *(const float4*)(Ag);      aHi0 = *(const float4*)(Ag + 4);
    stageB(0, 0);
    aLo1 = *(const float4*)(Ag + 32); aHi1 = *(const float4*)(Ag + 36);
    stageB(32, 1);
    *(usx8*)&As0[aWrOff] = packA(aLo0, aHi0);    // compiler auto-waits regs

    // fragment-read swizzle: ((16m + r16)>>1)&3 == (r16>>1)&3
    const int rxr = (r16 >> 1) & 3;

    #pragma unroll
    for (int k = 0; k < NITER; ++k) {
        const int cur = k % 3;
        const int stg = (k + 2) % 3;
        const int wnx = (k + 1) % 3;

        // P2: ds_write A for buf k+1 (regs loaded at iter k-1 / prologue).
        if (k + 1 < NITER) {
            usx8 w = ((k & 1) == 0) ? packA(aLo1, aHi1) : packA(aLo0, aHi0);
            *(usx8*)&As0[wnx * 4096 + aWrOff] = w;
        }
        // counted vm backstop + lgkm drain (own ds_write) + rendezvous
        if (k < NITER - 1) WAITV(4); else WAITV(0);
        WAITL0();
        BAR();

        // P1 (POST-BAR): issue stage for buf k+2
        if (k + 2 < NITER) {
            const int ko = (k + 2) * 32;
            if ((k & 1) == 0) {
                aLo0 = *(const float4*)(Ag + ko); aHi0 = *(const float4*)(Ag + ko + 4);
            } else {
                aLo1 = *(const float4*)(Ag + ko); aHi1 = *(const float4*)(Ag + ko + 4);
            }
            SBAR();
            stageB(ko, stg);
        }

        bf16x8 af[4], bfr[4];
        #pragma unroll
        for (int i = 0; i < 4; i++)
            af[i] = *(const bf16x8*)&As0[cur * 4096 + (wr * 64 + i * 16 + r16) * 32
                                         + ((quad ^ rxr) << 3)];
        #pragma unroll
        for (int j = 0; j < 4; j++)
            bfr[j] = *(const bf16x8*)&Bs0[cur * 8192 + (wc * 64 + j * 16 + r16) * 32
                                          + ((quad ^ rxr) << 3)];

        #pragma unroll
        for (int i = 0; i < 4; i++)
            #pragma unroll
            for (int j = 0; j < 4; j++)
                acc[i][j] = __builtin_amdgcn_mfma_f32_16x16x32_bf16(
                                bfr[j], af[i], acc[i][j], 0, 0, 0);  // swapped
    }

    // ---- epilogue part 1: xp tile (C + bias) -> LDS X[128][XLD] (bf16)
    __syncthreads();   // full drain; all waves done reading As/Bs
    #pragma unroll
    for (int i = 0; i < 4; i++) {
        const int ml = wr * 64 + i * 16 + r16;
        #pragma unroll
        for (int j = 0; j < 4; j++) {
            const int nl = wc * 64 + j * 16 + quad * 4;
            const float4 bv = *(const float4*)&b_in[bn * 256 + nl];
            ushort4 r4;
            r4.x = f2bf(acc[i][j][0] + bv.x);
            r4.y = f2bf(acc[i][j][1] + bv.y);
            r4.z = f2bf(acc[i][j][2] + bv.z);
            r4.w = f2bf(acc[i][j][3] + bv.w);
            *(ushort4*)&X[ml * XLD + nl] = r4;
        }
    }
    __syncthreads();

    // ---- epilogue part 2: chunk-local scan (prev = 0 at chunk start)
    const int chalf = tid >> 8;             // 0..1
    const int cidx  = tid & 255;            // 0..255
    const int g     = 2 * bm + chalf;       // global chunk 0..511
    const int d     = bn * 256 + cidx;      // 0..511
    const int h     = d >> 6;
    const float alpha = 1.0f / (1.0f + expf(-alpha_param[h]));
    const float c     = 1.0f - alpha;

    const ushort* Xr  = X + chalf * 64 * XLD + cidx;
    ushort* zrow = zout + ((size_t)(bm * 128 + chalf * 64)) * DIM + d;

    float z = 0.f, prev = 0.f;
    #pragma unroll 8
    for (int r = 0; r < CHUNK; ++r) {
        float xv = bf2f(Xr[r * XLD]);
        z = c * z + alpha * (xv - prev);
        prev = xv;
        zrow[(size_t)r * DIM] = f2bf(z);
    }
    Lfin[(size_t)g * 512 + d]       = z;     // L' tail
    XpT[(size_t)(g + 1) * 512 + d]  = prev;  // xp tail -> next chunk's xpt
}

// =====================================================================
// Carry chain:  G_k = c*Z_k - alpha*xpt_k ;  Z_{k+1} = L'_k + c^63 * G_k
// =====================================================================
__global__ void scan_fixg_kernel(const float* __restrict__ Lfin,
                                 const float* __restrict__ XpT,
                                 const float* __restrict__ alpha_param,
                                 const float* __restrict__ init_state,
                                 float* __restrict__ G)
{
    int ch = blockIdx.x * blockDim.x + threadIdx.x;   // 0..2047
    if (ch >= NCHAN) return;
    const int b = ch >> 9;
    const int d = ch & (DIM - 1);
    const int h = d >> 6;
    const float alpha = 1.0f / (1.0f + expf(-alpha_param[h]));
    const float c = 1.0f - alpha;
    const float c2 = c * c, c4 = c2 * c2, c8 = c4 * c4,
                c16 = c8 * c8, c32 = c16 * c16;
    const float c63 = c32 * c16 * c8 * c4 * c2 * c;
    const float sinit = init_state[d];

    float Z = sinit;
    const float* Lp = Lfin + (size_t)(b * NCHUNK) * 512 + d;
    const float* Xp = XpT  + (size_t)(b * NCHUNK) * 512 + d;
    float*       Gp = G    + (size_t)(b * NCHUNK) * 512 + d;

    constexpr int PF = 16;
    float Lr[PF], Xr[PF];
    #pragma unroll
    for (int j = 0; j < PF; ++j) {
        Lr[j] = Lp[(size_t)j * 512];
        Xr[j] = Xp[(size_t)j * 512];
    }
    for (int gr = 0; gr < NCHUNK / PF; ++gr) {        // 8 groups
        #pragma unroll
        for (int j = 0; j < PF; ++j) {
            const int kl = gr * PF + j;
            const float xpt = (kl == 0) ? sinit : Xr[j];
            const float Lc  = Lr[j];
            if (gr + 1 < NCHUNK / PF) {
                Lr[j] = Lp[(size_t)((gr + 1) * PF + j) * 512];
                Xr[j] = Xp[(size_t)((gr + 1) * PF + j) * 512];
            }
            const float Gv = c * Z - alpha * xpt;
            Gp[(size_t)kl * 512] = Gv;
            Z = Lc + c63 * Gv;
        }
    }
}

// =====================================================================
// GEMM2: out = z @ W_out^T + b_out ; carry correction fused in A-staging:
//   a[tau, d] += c_h^tau * G[g][d]   (g = row>>6, tau = row&63)
// Same race-fixed 3-buffer loop + corrected LDS XOR swizzle.
// =====================================================================
__global__ __launch_bounds__(512, 4) void gemm2_kernel(
        const ushort* __restrict__ Az, const ushort* __restrict__ Bw,
        const float* __restrict__ bias, float* __restrict__ Cout,
        const float* __restrict__ G, const float* __restrict__ alpha_param)
{
    __shared__ __align__(16) char smem[73728];
    ushort* As0 = (ushort*)smem;                 // 3 bufs x 4096 ushorts
    ushort* Bs0 = (ushort*)(smem + 24576);       // 3 bufs x 8192 ushorts

    const int tid  = threadIdx.x;
    const int lane = tid & 63;
    const int wave = tid >> 6;
    const int wr = wave >> 2, wc = wave & 3;
    const int bm = blockIdx.y, bn = blockIdx.x;
    const int quad = lane >> 4, r16 = lane & 15;

    const int srow  = tid >> 2;
    const int ks    = tid & 3;
    const int rx    = (srow >> 1) & 3;      // row-XOR (bits 1-2!)
    const int skoff = ks * 8;               // content k-offset
    const ushort* Ag16 = Az + (size_t)(bm * 128 + srow) * DIM + skoff;
    const ushort* Bg0  = Bw + (size_t)(bn * 256 + srow) * DIM + ((ks ^ rx) << 3);
    const ushort* Bg1  = Bg0 + (size_t)128 * DIM;
    const int aWrOff = srow * 32 + ((ks ^ rx) << 3);

    // per-thread fixed row -> fixed (g, tau); c_h^tau as named scalars
    const int m   = bm * 128 + srow;
    const int tau = m & (CHUNK - 1);
    const float* Gc = G + (size_t)(m >> 6) * 512;
    const float t1 = (float)tau;
    float fc0,fc1,fc2,fc3,fc4,fc5,fc6,fc7;
    {
        float a, c;
        a = 1.f/(1.f+expf(-alpha_param[0])); c = 1.f - a; fc0 = exp2f(t1 * log2f(c));
        a = 1.f/(1.f+expf(-alpha_param[1])); c = 1.f - a; fc1 = exp2f(t1 * log2f(c));
        a = 1.f/(1.f+expf(-alpha_param[2])); c = 1.f - a; fc2 = exp2f(t1 * log2f(c));
        a = 1.f/(1.f+expf(-alpha_param[3])); c = 1.f - a; fc3 = exp2f(t1 * log2f(c));
        a = 1.f/(1.f+expf(-alpha_param[4])); c = 1.f - a; fc4 = exp2f(t1 * log2f(c));
        a = 1.f/(1.f+expf(-alpha_param[5])); c = 1.f - a; fc5 = exp2f(t1 * log2f(c));
        a = 1.f/(1.f+expf(-alpha_param[6])); c = 1.f - a; fc6 = exp2f(t1 * log2f(c));
        a = 1.f/(1.f+expf(-alpha_param[7])); c = 1.f - a; fc7 = exp2f(t1 * log2f(c));
    }
    auto selfac = [&](int hh) -> float {
        float f = fc0;
        f = (hh == 1) ? fc1 : f;
        f = (hh == 2) ? fc2 : f;
        f = (hh == 3) ? fc3 : f;
        f = (hh == 4) ? fc4 : f;
        f = (hh == 5) ? fc5 : f;
        f = (hh == 6) ? fc6 : f;
        f = (hh == 7) ? fc7 : f;
        return f;
    };
    auto fixpack = [&](usx8 av, float4 z0, float4 z1, float fac) {
        usx8 w;
        w[0] = f2bf(bf2f(av[0]) + fac * z0.x);
        w[1] = f2bf(bf2f(av[1]) + fac * z0.y);
        w[2] = f2bf(bf2f(av[2]) + fac * z0.z);
        w[3] = f2bf(bf2f(av[3]) + fac * z0.w);
        w[4] = f2bf(bf2f(av[4]) + fac * z1.x);
        w[5] = f2bf(bf2f(av[5]) + fac * z1.y);
        w[6] = f2bf(bf2f(av[6]) + fac * z1.z);
        w[7] = f2bf(bf2f(av[7]) + fac * z1.w);
        return w;
    };

    f32x4 acc[4][4];
    #pragma unroll
    for (int i = 0; i < 4; i++)
        #pragma unroll
        for (int j = 0; j < 4; j++)
            acc[i][j] = f32x4{0.f, 0.f, 0.f, 0.f};

    auto stageB = [&](int k0, int b) {
        GLDS(Bg0 + k0, &Bs0[b * 8192 + tid * 8]);
        GLDS(Bg1 + k0, &Bs0[b * 8192 + 4096 + tid * 8]);
    };

    // A reg sets: data for buf j in set (j&1)
    usx8 av0, av1; float4 g0lo, g0hi, g1lo, g1hi;

    // prologue: issue stages for bufs 0,1; write fixed As[0]
    av0 = *(const usx8*)(Ag16);
    g0lo = *(const float4*)&Gc[skoff]; g0hi = *(const float4*)&Gc[skoff + 4];
    stageB(0, 0);
    av1 = *(const usx8*)(Ag16 + 32);
    g1lo = *(const float4*)&Gc[32 + skoff]; g1hi = *(const float4*)&Gc[32 + skoff + 4];
    stageB(32, 1);
    *(usx8*)&As0[aWrOff] = fixpack(av0, g0lo, g0hi, selfac(skoff >> 6));

    const int rxr = (r16 >> 1) & 3;

    #pragma unroll
    for (int k = 0; k < NITER; ++k) {
        const int cur = k % 3;
        const int stg = (k + 2) % 3;
        const int wnx = (k + 1) % 3;

        // P2: ds_write fixed A for buf k+1 (regs loaded at iter k-1)
        if (k + 1 < NITER) {
            const float fac = selfac((((k + 1) * 32) + skoff) >> 6);
            usx8 w = ((k & 1) == 0) ? fixpack(av1, g1lo, g1hi, fac)
                                    : fixpack(av0, g0lo, g0hi, fac);
            *(usx8*)&As0[wnx * 4096 + aWrOff] = w;
        }
        if (k < NITER - 1) WAITV(5); else WAITV(0);
        WAITL0();
        BAR();

        // P1 (POST-BAR): issue stage for buf k+2
        if (k + 2 < NITER) {
            const int ko = (k + 2) * 32;
            if ((k & 1) == 0) {
                av0 = *(const usx8*)(Ag16 + ko);
                g0lo = *(const float4*)&Gc[ko + skoff];
                g0hi = *(const float4*)&Gc[ko + skoff + 4];
            } else {
                av1 = *(const usx8*)(Ag16 + ko);
                g1lo = *(const float4*)&Gc[ko + skoff];
                g1hi = *(const float4*)&Gc[ko + skoff + 4];
            }
            SBAR();
            stageB(ko, stg);
        }

        bf16x8 af[4], bfr[4];
        #pragma unroll
        for (int i = 0; i < 4; i++)
            af[i] = *(const bf16x8*)&As0[cur * 4096 + (wr * 64 + i * 16 + r16) * 32
                                         + ((quad ^ rxr) << 3)];
        #pragma unroll
        for (int j = 0; j < 4; j++)
            bfr[j] = *(const bf16x8*)&Bs0[cur * 8192 + (wc * 64 + j * 16 + r16) * 32
                                          + ((quad ^ rxr) << 3)];

        #pragma unroll
        for (int i = 0; i < 4; i++)
            #pragma unroll
            for (int j = 0; j < 4; j++)
                acc[i][j] = __builtin_amdgcn_mfma_f32_16x16x32_bf16(
                                bfr[j], af[i], acc[i][j], 0, 0, 0);  // swapped
    }

    // epilogue: m = lane&15 (per i-tile), n = quad*4 + reg
    #pragma unroll
    for (int i = 0; i < 4; i++) {
        const int mr = bm * 128 + wr * 64 + i * 16 + r16;
        #pragma unroll
        for (int j = 0; j < 4; j++) {
            const int n0 = bn * 256 + wc * 64 + j * 16 + quad * 4;
            const float4 bv = *(const float4*)&bias[n0];
            float4 v = make_float4(acc[i][j][0] + bv.x, acc[i][j][1] + bv.y,
                                   acc[i][j][2] + bv.z, acc[i][j][3] + bv.w);
            *(float4*)&Cout[(size_t)mr * DIM + n0] = v;
        }
    }
}

extern "C" void kernel_launch(void* const* d_in, const int* in_sizes, int n_in,
                              void* d_out, int out_size, void* d_ws, size_t ws_size,
                              hipStream_t stream) {
    const float* x           = (const float*)d_in[0];
    const float* W_in        = (const float*)d_in[1];
    const float* b_in        = (const float*)d_in[2];
    const float* W_out       = (const float*)d_in[3];
    const float* b_out       = (const float*)d_in[4];
    const float* init_state  = (const float*)d_in[5];
    const float* alpha_param = (const float*)d_in[6];
    float* out = (float*)d_out;

    // workspace layout
    ushort* z_bf    = (ushort*)d_ws;                       // 32 MB
    ushort* win_bf  = z_bf   + (size_t)MROWS * DIM;        // 0.5 MB
    ushort* wout_bf = win_bf + (size_t)DIM * DIM;          // 0.5 MB
    float*  Lfin    = (float*)(wout_bf + (size_t)DIM * DIM);        // [512][512]
    float*  XpT     = Lfin + (size_t)NGCHUNK * 512;                 // [513][512]
    float*  G       = XpT  + (size_t)(NGCHUNK + 1) * 512;           // [512][512]

    const int nw4 = (DIM * DIM) / 4;          // 65,536
    weights_to_bf16_kernel<<<(2 * nw4 + 255) / 256, 256, 0, stream>>>(
        W_in, W_out, win_bf, nw4);

    dim3 g1(2, MROWS / 128);                  // (2, 256)
    gemm1_scan_kernel<<<g1, 512, 0, stream>>>(
        x, win_bf, b_in, alpha_param, z_bf, Lfin, XpT);

    scan_fixg_kernel<<<NCHAN / 256, 256, 0, stream>>>(
        Lfin, XpT, alpha_param, init_state, G);

    dim3 g2(2, MROWS / 128);                  // (2, 256)
    gemm2_kernel<<<g2, 512, 0, stream>>>(
        z_bf, wout_bf, b_out, out, G, alpha_param);
}